// Round 4
// baseline (558.928 us; speedup 1.0000x reference)
//
#include <hip/hip_runtime.h>
#include <hip/hip_cooperative_groups.h>
#include <math.h>

#define T_ 8
#define B_ 4
#define C_ 128
#define HW_ 9216        // 96*96
#define IN_HW_ 147456   // 384*384

typedef float nat_f4 __attribute__((ext_vector_type(4)));  // nontemporal stores

// ---------------------------------------------------------------------------
// Bilinear antialias resize 384 -> 96: separable 8-tap triangle filter.
// (unchanged -- binarization threshold must match the f64 reference exactly)
// ---------------------------------------------------------------------------
__device__ __forceinline__ double resize_px(const float* __restrict__ img, int y, int x) {
  static const double wm[8]  = {0.03125, 0.09375, 0.15625, 0.21875,
                                0.21875, 0.15625, 0.09375, 0.03125};
  static const double w0[8]  = {0.0, 0.0, 0.625/3.5, 0.875/3.5,
                                0.875/3.5, 0.625/3.5, 0.375/3.5, 0.125/3.5};
  static const double w95[8] = {0.125/3.5, 0.375/3.5, 0.625/3.5, 0.875/3.5,
                                0.875/3.5, 0.625/3.5, 0.0, 0.0};
  const double* wy = (y == 0) ? w0 : (y == 95 ? w95 : wm);
  const double* wx = (x == 0) ? w0 : (x == 95 ? w95 : wm);
  double acc = 0.0;
#pragma unroll
  for (int ky = 0; ky < 8; ++ky) {
    double wyv = wy[ky];
    if (wyv == 0.0) continue;
    int jy = 4 * y - 2 + ky;
    const float* row = img + jy * 384;
    double ra = 0.0;
#pragma unroll
    for (int kx = 0; kx < 8; ++kx) {
      double wxv = wx[kx];
      if (wxv == 0.0) continue;
      int jx = 4 * x - 2 + kx;
      ra += wxv * (double)row[jx];
    }
    acc += wyv * ra;
  }
  return acc;
}

// shuffle+LDS block sum (256 threads). Trailing sync: safe to call repeatedly.
__device__ __forceinline__ float block_sum_256(float v) {
  v += __shfl_xor(v, 1);
  v += __shfl_xor(v, 2);
  v += __shfl_xor(v, 4);
  v += __shfl_xor(v, 8);
  v += __shfl_xor(v, 16);
  v += __shfl_xor(v, 32);
  __shared__ float s[4];
  int lane = threadIdx.x & 63, wv = threadIdx.x >> 6;
  if (lane == 0) s[wv] = v;
  __syncthreads();
  float r = s[0] + s[1] + s[2] + s[3];
  __syncthreads();
  return r;
}

// ---------------------------------------------------------------------------
// Phase device functions — shared verbatim by the cooperative fused kernel
// and the 4-launch fallback path (bit-identical results either way).
// ---------------------------------------------------------------------------

// A: rv/vm generation (resize+binarize). 1152 jobs of 256 px.
__device__ __forceinline__ void phaseA(int bid, int nb,
                                       const float* __restrict__ rvmaps,
                                       const float* __restrict__ tvmap,
                                       float* __restrict__ rv,
                                       float* __restrict__ vm) {
  const int tid = threadIdx.x;
  for (int job = bid; job < 1152; job += nb) {
    int tb = job / 36;                  // t*B + b
    int b  = tb % B_;
    int p  = (job % 36) * 256 + tid;
    int y = p / 96, x = p % 96;
    float rvv = (resize_px(rvmaps + (size_t)tb * IN_HW_, y, x) > 0.5) ? 1.0f : 0.0f;
    float tvv = (resize_px(tvmap  + (size_t)b  * IN_HW_, y, x) > 0.5) ? 1.0f : 0.0f;
    rv[(size_t)tb * HW_ + p] = rvv;
    vm[(size_t)tb * HW_ + p] = rvv * tvv;
  }
}

// B: gs partial tiles (jobs 0..4607) + v_sum reductions (jobs 4608..4639).
__device__ __forceinline__ void phaseB(int bid, int nb,
                                       const float* __restrict__ values,
                                       const float* __restrict__ vm,
                                       float* __restrict__ gs_part,
                                       float* __restrict__ v_sum) {
  const int tid = threadIdx.x;
  __shared__ float sred[4][T_];
  for (int job = bid; job < 4640; job += nb) {
    if (job < 4608) {
      int ptile = job % 9;
      int c     = (job / 9) % C_;
      int b     = job / (9 * C_);
      int p0 = ptile * 1024 + tid * 4;
      const float4 a = *(const float4*)(values + ((size_t)b * C_ + c) * HW_ + p0);
      float acc[T_];
#pragma unroll
      for (int t = 0; t < T_; ++t) {
        const float4 m = *(const float4*)(vm + ((size_t)(t * B_ + b)) * HW_ + p0);
        const float4 r = *(const float4*)(values + ((size_t)((1 + t) * B_ + b) * C_ + c) * HW_ + p0);
        acc[t] = m.x * a.x * r.x + m.y * a.y * r.y + m.z * a.z * r.z + m.w * a.w * r.w;
      }
      int lane = tid & 63, wv = tid >> 6;
#pragma unroll
      for (int t = 0; t < T_; ++t) {
        float v = acc[t];
        v += __shfl_xor(v, 1);
        v += __shfl_xor(v, 2);
        v += __shfl_xor(v, 4);
        v += __shfl_xor(v, 8);
        v += __shfl_xor(v, 16);
        v += __shfl_xor(v, 32);
        if (lane == 0) sred[wv][t] = v;
      }
      __syncthreads();
      if (tid < T_) {
        int t = tid;
        float s = sred[0][t] + sred[1][t] + sred[2][t] + sred[3][t];
        gs_part[(size_t)(t * B_ + b) * (C_ * 9) + c * 9 + ptile] = s;
      }
      __syncthreads();     // protect sred before next job reuses it
    } else {
      int tb = job - 4608;                       // 0..31
      const float4* p = (const float4*)(vm + (size_t)tb * HW_);
      float s = 0.f;
      for (int i = tid; i < HW_ / 4; i += 256) { // 9 float4 per thread
        float4 v = p[i];
        s += v.x + v.y + v.z + v.w;
      }
      s = block_sum_256(s);                      // exact: sum of 0/1 floats
      if (tid == 0) v_sum[tb] = s;
    }
  }
}

// C: gs finalize (32 blocks, one per tb).
__device__ __forceinline__ void phaseC(int bid,
                                       const float* __restrict__ gs_part,
                                       const float* __restrict__ v_sum,
                                       float* __restrict__ gsar,
                                       float* __restrict__ out_gs) {
  const int tid = threadIdx.x;
  if (bid < T_ * B_) {
    int tb = bid;
    const float4* p = (const float4*)(gs_part + (size_t)tb * (C_ * 9));
    float s = 0.f;
    for (int i = tid; i < (C_ * 9) / 4; i += 256) {   // 288 float4
      float4 v = p[i];
      s += v.x + v.y + v.z + v.w;
    }
    s = block_sum_256(s);
    if (tid == 0) {
      float vs = v_sum[tb];
      bool empty = vs < 1e-4f;
      float g = (empty ? 0.f : s) / (vs + (empty ? 1.f : 0.f)) / (float)C_;
      gsar[tb] = g;
      out_gs[tb] = g;
    }
  }
}

// E: softmax + t_feat passthrough + c_out + c_mask. 1152 jobs.
// gs read as uniform scalar loads (no shared, no per-job sync).
__device__ __forceinline__ void phaseE(int bid, int nb,
                                       const float* __restrict__ values,
                                       const float* __restrict__ rv,
                                       const float* __restrict__ gsar,
                                       float* __restrict__ out,
                                       float* __restrict__ out_cmask) {
  const int tid = threadIdx.x;
  for (int job = bid; job < 1152; job += nb) {
    int b     = job / 288;
    int rem   = job % 288;
    int ptile = rem / 32;
    int ctile = rem % 32;

    float gsv[T_];
#pragma unroll
    for (int t = 0; t < T_; ++t) gsv[t] = gsar[t * B_ + b];  // uniform loads

    int p0 = ptile * 1024 + tid * 4;
    float4 rv4[T_];
#pragma unroll
    for (int t = 0; t < T_; ++t)
      rv4[t] = *(const float4*)(rv + ((size_t)(t * B_ + b)) * HW_ + p0);

    float cm[T_][4];
    float cmask[4];
#pragma unroll
    for (int j = 0; j < 4; ++j) {
      float mv[T_];
      float mx = -1e30f;
#pragma unroll
      for (int t = 0; t < T_; ++t) {
        float rvv = ((const float*)&rv4[t])[j];
        mv[t] = gsv[t] * rvv;
        mx = fmaxf(mx, mv[t]);
      }
      float e[T_];
      float ms = 0.f;
#pragma unroll
      for (int t = 0; t < T_; ++t) {
        float rvv = ((const float*)&rv4[t])[j];
        e[t] = expf(mv[t] - mx) * rvv;
        ms += e[t];
      }
      if (ms < 1e-4f) ms += 1.f;
      float inv = 1.f / ms;
      float cs = 0.f;
#pragma unroll
      for (int t = 0; t < T_; ++t) {
        cm[t][j] = e[t] * inv;
        cs += cm[t][j] * ((const float*)&rv4[t])[j];
      }
      cmask[j] = 1.f - cs;
    }

    size_t outb = (size_t)b * 257 * HW_;
#pragma unroll 1
    for (int cc = 0; cc < 4; ++cc) {
      int c = ctile * 4 + cc;
      const float4 tf = *(const float4*)(values + ((size_t)b * C_ + c) * HW_ + p0);
      nat_f4 tfn = {tf.x, tf.y, tf.z, tf.w};
      __builtin_nontemporal_store(tfn, (nat_f4*)(out + outb + (size_t)c * HW_ + p0));
      float4 acc = {0.f, 0.f, 0.f, 0.f};
#pragma unroll
      for (int t = 0; t < T_; ++t) {
        const float4 r = *(const float4*)(values +
            ((size_t)((1 + t) * B_ + b) * C_ + c) * HW_ + p0);
        acc.x += cm[t][0] * r.x;
        acc.y += cm[t][1] * r.y;
        acc.z += cm[t][2] * r.z;
        acc.w += cm[t][3] * r.w;
      }
      nat_f4 accn = {acc.x, acc.y, acc.z, acc.w};
      __builtin_nontemporal_store(accn, (nat_f4*)(out + outb + (size_t)(C_ + c) * HW_ + p0));
    }
    if (ctile == 0) {
      nat_f4 cmv = {cmask[0], cmask[1], cmask[2], cmask[3]};
      __builtin_nontemporal_store(cmv, (nat_f4*)(out + outb + (size_t)256 * HW_ + p0));
      __builtin_nontemporal_store(cmv, (nat_f4*)(out_cmask + (size_t)b * HW_ + p0));
    }
  }
}

// ---------------------------------------------------------------------------
// Cooperative fused kernel + 4 standalone fallback kernels.
// ---------------------------------------------------------------------------
__global__ __launch_bounds__(256, 4) void k_fused(
    const float* __restrict__ values, const float* __restrict__ tvmap,
    const float* __restrict__ rvmaps, float* __restrict__ rv,
    float* __restrict__ vm, float* __restrict__ gs_part,
    float* __restrict__ v_sum, float* __restrict__ gsar,
    float* __restrict__ out, float* __restrict__ out_cmask,
    float* __restrict__ out_gs) {
  cooperative_groups::grid_group grid = cooperative_groups::this_grid();
  phaseA(blockIdx.x, gridDim.x, rvmaps, tvmap, rv, vm);
  grid.sync();
  phaseB(blockIdx.x, gridDim.x, values, vm, gs_part, v_sum);
  grid.sync();
  phaseC(blockIdx.x, gs_part, v_sum, gsar, out_gs);
  grid.sync();
  phaseE(blockIdx.x, gridDim.x, values, rv, gsar, out, out_cmask);
}

__global__ __launch_bounds__(256) void k_pA(const float* __restrict__ rvmaps,
                                            const float* __restrict__ tvmap,
                                            float* __restrict__ rv, float* __restrict__ vm) {
  phaseA(blockIdx.x, gridDim.x, rvmaps, tvmap, rv, vm);
}
__global__ __launch_bounds__(256) void k_pB(const float* __restrict__ values,
                                            const float* __restrict__ vm,
                                            float* __restrict__ gs_part,
                                            float* __restrict__ v_sum) {
  phaseB(blockIdx.x, gridDim.x, values, vm, gs_part, v_sum);
}
__global__ __launch_bounds__(256) void k_pC(const float* __restrict__ gs_part,
                                            const float* __restrict__ v_sum,
                                            float* __restrict__ gsar,
                                            float* __restrict__ out_gs) {
  phaseC(blockIdx.x, gs_part, v_sum, gsar, out_gs);
}
__global__ __launch_bounds__(256) void k_pE(const float* __restrict__ values,
                                            const float* __restrict__ rv,
                                            const float* __restrict__ gsar,
                                            float* __restrict__ out,
                                            float* __restrict__ out_cmask) {
  phaseE(blockIdx.x, gridDim.x, values, rv, gsar, out, out_cmask);
}

extern "C" void kernel_launch(void* const* d_in, const int* in_sizes, int n_in,
                              void* d_out, int out_size, void* d_ws, size_t ws_size,
                              hipStream_t stream) {
  const float* values = (const float*)d_in[0];   // (9,4,128,96,96)
  const float* tvmap  = (const float*)d_in[1];   // (4,1,384,384)
  const float* rvmaps = (const float*)d_in[2];   // (8,4,1,384,384)
  float* out = (float*)d_out;

  // workspace layout (floats)
  float* ws      = (float*)d_ws;
  float* rv      = ws;                                   // T*B*HW = 294912
  float* vm      = rv + (size_t)T_ * B_ * HW_;           // T*B*HW = 294912
  float* gs_part = vm + (size_t)T_ * B_ * HW_;           // T*B*C*9 = 36864
  float* v_sum   = gs_part + (size_t)T_ * B_ * C_ * 9;   // 32
  float* gsar    = v_sum + T_ * B_;                      // 32

  // output layout: out(4,257,96,96) | c_mask(4,1,96,96) | gs(8,4)
  float* out_cmask = out + (size_t)B_ * 257 * HW_;
  float* out_gs    = out_cmask + (size_t)B_ * HW_;

  // Co-resident grid for the cooperative path (cached across calls).
  static int coop_grid = 0;
  if (coop_grid == 0) {
    int maxb = 0;
    hipError_t qe = hipOccupancyMaxActiveBlocksPerMultiprocessor(&maxb, k_fused, 256, 0);
    if (qe != hipSuccess || maxb < 1) coop_grid = -1;     // no cooperative
    else {
      long g = (long)maxb * 256;                          // 256 CUs
      coop_grid = (int)(g > 1024 ? 1024 : g);
    }
  }

  hipError_t e = hipErrorUnknown;
  if (coop_grid > 0) {
    void* args[] = {(void*)&values, (void*)&tvmap, (void*)&rvmaps,
                    (void*)&rv, (void*)&vm, (void*)&gs_part, (void*)&v_sum,
                    (void*)&gsar, (void*)&out, (void*)&out_cmask, (void*)&out_gs};
    e = hipLaunchCooperativeKernel((const void*)k_fused, dim3(coop_grid),
                                   dim3(256), args, 0, stream);
    if (e != hipSuccess) coop_grid = -1;   // remember: fall back from now on
  }
  if (e != hipSuccess) {
    // Fallback: identical phases as 4 regular launches.
    hipLaunchKernelGGL(k_pA, dim3(1152), dim3(256), 0, stream, rvmaps, tvmap, rv, vm);
    hipLaunchKernelGGL(k_pB, dim3(4640), dim3(256), 0, stream, values, vm, gs_part, v_sum);
    hipLaunchKernelGGL(k_pC, dim3(32),   dim3(256), 0, stream, gs_part, v_sum, gsar, out_gs);
    hipLaunchKernelGGL(k_pE, dim3(1152), dim3(256), 0, stream, values, rv, gsar, out, out_cmask);
  }
}

// Round 5
// 322.104 us; speedup vs baseline: 1.7352x; 1.7352x over previous
//
#include <hip/hip_runtime.h>
#include <math.h>

#define T_ 8
#define B_ 4
#define C_ 128
#define HW_ 9216        // 96*96
#define IN_HW_ 147456   // 384*384

typedef float nat_f4 __attribute__((ext_vector_type(4)));  // nontemporal stores

// f64 filter weights (8-tap triangle, edge-renormalized)
__device__ static const double d_wm[8]  = {0.03125, 0.09375, 0.15625, 0.21875,
                                           0.21875, 0.15625, 0.09375, 0.03125};
__device__ static const double d_w0[8]  = {0.0, 0.0, 0.625/3.5, 0.875/3.5,
                                           0.875/3.5, 0.625/3.5, 0.375/3.5, 0.125/3.5};
__device__ static const double d_w95[8] = {0.125/3.5, 0.375/3.5, 0.625/3.5, 0.875/3.5,
                                           0.875/3.5, 0.625/3.5, 0.0, 0.0};

// shuffle+LDS block sum (256 threads). Trailing sync: safe to call repeatedly.
__device__ __forceinline__ float block_sum_256(float v) {
  v += __shfl_xor(v, 1);
  v += __shfl_xor(v, 2);
  v += __shfl_xor(v, 4);
  v += __shfl_xor(v, 8);
  v += __shfl_xor(v, 16);
  v += __shfl_xor(v, 32);
  __shared__ float s[4];
  int lane = threadIdx.x & 63, wv = threadIdx.x >> 6;
  if (lane == 0) s[wv] = v;
  __syncthreads();
  float r = s[0] + s[1] + s[2] + s[3];
  __syncthreads();
  return r;
}

// ---------------------------------------------------------------------------
// k_resize: 384->96 antialias resize + binarize for all 36 mask images.
// grid (6, 36): y = 0..35 (0..31: rv image tb; 32..35: tv image b).
// block 384 threads: x = tid%96, yg = tid/96; thread computes 4 vertical
// pixels (y0..y0+3). Row filter value ra is shared by all 4 pixels (same x);
// per-pixel accumulation order identical to the verified scalar version
// (kx then ky ascending, zero-weight taps contribute exact +0 on non-negative
// data) => bit-identical binarization.
// ---------------------------------------------------------------------------
__global__ __launch_bounds__(384) void k_resize(const float* __restrict__ rvmaps,
                                                const float* __restrict__ tvmap,
                                                float* __restrict__ rv,
                                                float* __restrict__ tv) {
  const int job = blockIdx.y;
  const float* img = (job < 32) ? rvmaps + (size_t)job * IN_HW_
                                : tvmap  + (size_t)(job - 32) * IN_HW_;
  float* dst = (job < 32) ? rv + (size_t)job * HW_
                          : tv + (size_t)(job - 32) * HW_;
  const int x  = threadIdx.x % 96;
  const int yg = threadIdx.x / 96;           // 0..3
  const int y0 = blockIdx.x * 16 + yg * 4;   // 4 output rows per thread

  // y-weight tables per pixel
  const double* wys[4];
#pragma unroll
  for (int i = 0; i < 4; ++i) {
    int y = y0 + i;
    wys[i] = (y == 0) ? d_w0 : (y == 95 ? d_w95 : d_wm);
  }

  double acc0 = 0.0, acc1 = 0.0, acc2 = 0.0, acc3 = 0.0;
  const int base = 4 * y0 - 2;                       // ky = jy - base - 4*i
  const int jy_lo = base < 0 ? 0 : base;
  const int jy_hi_raw = 4 * (y0 + 3) + 5;
  const int jy_hi = jy_hi_raw > 383 ? 383 : jy_hi_raw;

  for (int jy = jy_lo; jy <= jy_hi; ++jy) {
    const float* row = img + (size_t)jy * 384;
    double ra;
    if (x == 0) {
      const float4 q0 = *(const float4*)(row);       // jx 0..3
      const float4 q1 = *(const float4*)(row + 4);   // jx 4..7
      ra = d_w0[2] * (double)q0.x + d_w0[3] * (double)q0.y +
           d_w0[4] * (double)q0.z + d_w0[5] * (double)q0.w +
           d_w0[6] * (double)q1.x + d_w0[7] * (double)q1.y;
    } else if (x == 95) {
      const float4 q0 = *(const float4*)(row + 376); // jx 376..379
      const float4 q1 = *(const float4*)(row + 380); // jx 380..383
      ra = d_w95[0] * (double)q0.z + d_w95[1] * (double)q0.w +
           d_w95[2] * (double)q1.x + d_w95[3] * (double)q1.y +
           d_w95[4] * (double)q1.z + d_w95[5] * (double)q1.w;
    } else {
      const int b0 = 4 * x - 4;                      // multiple of 4 -> 16B aligned
      const float4 q0 = *(const float4*)(row + b0);
      const float4 q1 = *(const float4*)(row + b0 + 4);
      const float4 q2 = *(const float4*)(row + b0 + 8);
      // window = elements 2..9 of the 12 loaded (jx = 4x-2 .. 4x+5)
      ra = d_wm[0] * (double)q0.z + d_wm[1] * (double)q0.w +
           d_wm[2] * (double)q1.x + d_wm[3] * (double)q1.y +
           d_wm[4] * (double)q1.z + d_wm[5] * (double)q1.w +
           d_wm[6] * (double)q2.x + d_wm[7] * (double)q2.y;
    }
    // accumulate into the (up to 4) output pixels using this row
    {
      int ky = jy - base;
      if (ky >= 0 && ky < 8) acc0 += wys[0][ky] * ra;
      ky -= 4;
      if (ky >= 0 && ky < 8) acc1 += wys[1][ky] * ra;
      ky -= 4;
      if (ky >= 0 && ky < 8) acc2 += wys[2][ky] * ra;
      ky -= 4;
      if (ky >= 0 && ky < 8) acc3 += wys[3][ky] * ra;
    }
  }
  dst[(size_t)(y0 + 0) * 96 + x] = (acc0 > 0.5) ? 1.0f : 0.0f;
  dst[(size_t)(y0 + 1) * 96 + x] = (acc1 > 0.5) ? 1.0f : 0.0f;
  dst[(size_t)(y0 + 2) * 96 + x] = (acc2 > 0.5) ? 1.0f : 0.0f;
  dst[(size_t)(y0 + 3) * 96 + x] = (acc3 > 0.5) ? 1.0f : 0.0f;
}

// ---------------------------------------------------------------------------
// k_gs: t-major gs partials + t_feat passthrough. block = (ptile, c, b).
// m = rv*tv computed inline (exact 0/1 product == old precomputed vm).
// grid: (9, C_, B_), 256 threads, 1 float4 per tensor per thread.
// ---------------------------------------------------------------------------
__global__ __launch_bounds__(256) void k_gs(const float* __restrict__ values,
                                            const float* __restrict__ rv,
                                            const float* __restrict__ tv,
                                            float* __restrict__ gs_part,
                                            float* __restrict__ out) {
  const int ptile = blockIdx.x;       // 0..8
  const int c     = blockIdx.y;       // 0..127
  const int b     = blockIdx.z;       // 0..3
  const int tid   = threadIdx.x;
  const int p0 = ptile * 1024 + tid * 4;

  const float4 a   = *(const float4*)(values + ((size_t)b * C_ + c) * HW_ + p0);
  const float4 tvv = *(const float4*)(tv + (size_t)b * HW_ + p0);

  // t_feat passthrough (out channels 0..127) -- we already loaded the tile
  {
    nat_f4 an = {a.x, a.y, a.z, a.w};
    __builtin_nontemporal_store(an,
        (nat_f4*)(out + (size_t)b * 257 * HW_ + (size_t)c * HW_ + p0));
  }

  float acc[T_];
#pragma unroll
  for (int t = 0; t < T_; ++t) {
    const float4 rv4 = *(const float4*)(rv + ((size_t)(t * B_ + b)) * HW_ + p0);
    const float4 r = *(const float4*)(values + ((size_t)((1 + t) * B_ + b) * C_ + c) * HW_ + p0);
    const float mx_ = rv4.x * tvv.x, my_ = rv4.y * tvv.y;
    const float mz_ = rv4.z * tvv.z, mw_ = rv4.w * tvv.w;
    acc[t] = mx_ * a.x * r.x + my_ * a.y * r.y + mz_ * a.z * r.z + mw_ * a.w * r.w;
  }

  __shared__ float sred[4][T_];
  const int lane = tid & 63, wv = tid >> 6;
#pragma unroll
  for (int t = 0; t < T_; ++t) {
    float v = acc[t];
    v += __shfl_xor(v, 1);
    v += __shfl_xor(v, 2);
    v += __shfl_xor(v, 4);
    v += __shfl_xor(v, 8);
    v += __shfl_xor(v, 16);
    v += __shfl_xor(v, 32);
    if (lane == 0) sred[wv][t] = v;
  }
  __syncthreads();
  if (tid < T_) {
    const int t = tid;
    const float s = sred[0][t] + sred[1][t] + sred[2][t] + sred[3][t];
    gs_part[(size_t)(t * B_ + b) * (C_ * 9) + c * 9 + ptile] = s;
  }
}

// ---------------------------------------------------------------------------
// k_fin: per-tb v_sum (exact 0/1 sum of rv*tv) + gs_part reduce + finalize.
// grid: 32 blocks x 256.
// ---------------------------------------------------------------------------
__global__ __launch_bounds__(256) void k_fin(const float* __restrict__ rv,
                                             const float* __restrict__ tv,
                                             const float* __restrict__ gs_part,
                                             float* __restrict__ gsar,
                                             float* __restrict__ out_gs) {
  const int tb = blockIdx.x;          // 0..31
  const int b  = tb % B_;
  const int tid = threadIdx.x;

  const float4* pr = (const float4*)(rv + (size_t)tb * HW_);
  const float4* pt = (const float4*)(tv + (size_t)b  * HW_);
  float vs = 0.f;
  for (int i = tid; i < HW_ / 4; i += 256) {     // 9 iters
    const float4 r = pr[i], t = pt[i];
    vs += r.x * t.x + r.y * t.y + r.z * t.z + r.w * t.w;
  }
  vs = block_sum_256(vs);                        // exact: sum of 0/1 floats

  const float4* pg = (const float4*)(gs_part + (size_t)tb * (C_ * 9));
  float s = 0.f;
  for (int i = tid; i < (C_ * 9) / 4; i += 256) {  // 288 float4
    const float4 v = pg[i];
    s += v.x + v.y + v.z + v.w;
  }
  s = block_sum_256(s);

  if (tid == 0) {
    const bool empty = vs < 1e-4f;
    const float g = (empty ? 0.f : s) / (vs + (empty ? 1.f : 0.f)) / (float)C_;
    gsar[tb] = g;
    out_gs[tb] = g;
  }
}

// ---------------------------------------------------------------------------
// k_epi: per-pixel softmax over t (recomputed per ctile -- VALU is idle),
// c_out (out channels 128..255), cmask (channel 256 + out_cmask).
// grid: (32 ctiles of 4 ch, 9 ptiles, B_), 4 px/thread (float4).
// ---------------------------------------------------------------------------
__global__ __launch_bounds__(256) void k_epi(const float* __restrict__ values,
                                             const float* __restrict__ rv,
                                             const float* __restrict__ gs,
                                             float* __restrict__ out,
                                             float* __restrict__ out_cmask) {
  const int ctile = blockIdx.x;       // 0..31
  const int ptile = blockIdx.y;       // 0..8
  const int b     = blockIdx.z;       // 0..3
  const int tid   = threadIdx.x;
  __shared__ float gsh[T_];
  if (tid < T_) gsh[tid] = gs[tid * B_ + b];
  __syncthreads();

  const int p0 = ptile * 1024 + tid * 4;

  float4 rv4[T_];
#pragma unroll
  for (int t = 0; t < T_; ++t)
    rv4[t] = *(const float4*)(rv + ((size_t)(t * B_ + b)) * HW_ + p0);

  float cm[T_][4];
  float cmask[4];
#pragma unroll
  for (int j = 0; j < 4; ++j) {
    float mv[T_];
    float mx = -1e30f;
#pragma unroll
    for (int t = 0; t < T_; ++t) {
      const float rvv = ((const float*)&rv4[t])[j];
      mv[t] = gsh[t] * rvv;
      mx = fmaxf(mx, mv[t]);
    }
    float e[T_];
    float ms = 0.f;
#pragma unroll
    for (int t = 0; t < T_; ++t) {
      const float rvv = ((const float*)&rv4[t])[j];
      e[t] = expf(mv[t] - mx) * rvv;
      ms += e[t];
    }
    if (ms < 1e-4f) ms += 1.f;
    const float inv = 1.f / ms;
    float cs = 0.f;
#pragma unroll
    for (int t = 0; t < T_; ++t) {
      cm[t][j] = e[t] * inv;
      cs += cm[t][j] * ((const float*)&rv4[t])[j];
    }
    cmask[j] = 1.f - cs;
  }

  const size_t outb = (size_t)b * 257 * HW_;
#pragma unroll 1
  for (int cc = 0; cc < 4; ++cc) {
    const int c = ctile * 4 + cc;
    float4 acc = {0.f, 0.f, 0.f, 0.f};
#pragma unroll
    for (int t = 0; t < T_; ++t) {
      const float4 r = *(const float4*)(values +
          ((size_t)((1 + t) * B_ + b) * C_ + c) * HW_ + p0);
      acc.x += cm[t][0] * r.x;
      acc.y += cm[t][1] * r.y;
      acc.z += cm[t][2] * r.z;
      acc.w += cm[t][3] * r.w;
    }
    nat_f4 accn = {acc.x, acc.y, acc.z, acc.w};
    __builtin_nontemporal_store(accn, (nat_f4*)(out + outb + (size_t)(C_ + c) * HW_ + p0));
  }
  if (ctile == 0) {
    nat_f4 cmv = {cmask[0], cmask[1], cmask[2], cmask[3]};
    __builtin_nontemporal_store(cmv, (nat_f4*)(out + outb + (size_t)256 * HW_ + p0));
    __builtin_nontemporal_store(cmv, (nat_f4*)(out_cmask + (size_t)b * HW_ + p0));
  }
}

extern "C" void kernel_launch(void* const* d_in, const int* in_sizes, int n_in,
                              void* d_out, int out_size, void* d_ws, size_t ws_size,
                              hipStream_t stream) {
  const float* values = (const float*)d_in[0];   // (9,4,128,96,96)
  const float* tvmap  = (const float*)d_in[1];   // (4,1,384,384)
  const float* rvmaps = (const float*)d_in[2];   // (8,4,1,384,384)
  float* out = (float*)d_out;

  // workspace layout (floats) -- ~1.5 MB
  float* ws      = (float*)d_ws;
  float* rv      = ws;                                   // T*B*HW = 294912
  float* tv      = rv + (size_t)T_ * B_ * HW_;           // B*HW   = 36864
  float* gs_part = tv + (size_t)B_ * HW_;                // T*B*C*9 = 36864
  float* gsar    = gs_part + (size_t)T_ * B_ * C_ * 9;   // 32

  // output layout: out(4,257,96,96) | c_mask(4,1,96,96) | gs(8,4)
  float* out_cmask = out + (size_t)B_ * 257 * HW_;
  float* out_gs    = out_cmask + (size_t)B_ * HW_;

  hipLaunchKernelGGL(k_resize, dim3(6, 36),      dim3(384), 0, stream, rvmaps, tvmap, rv, tv);
  hipLaunchKernelGGL(k_gs,     dim3(9, C_, B_),  dim3(256), 0, stream, values, rv, tv, gs_part, out);
  hipLaunchKernelGGL(k_fin,    dim3(32),         dim3(256), 0, stream, rv, tv, gs_part, gsar, out_gs);
  hipLaunchKernelGGL(k_epi,    dim3(32, 9, B_),  dim3(256), 0, stream, values, rv, gsar, out, out_cmask);
}